// Round 2
// baseline (2437.413 us; speedup 1.0000x reference)
//
#include <hip/hip_runtime.h>
#include <hip/hip_bf16.h>

#define BN_EPS 1e-5f
#define WAVE_BARRIER() __builtin_amdgcn_wave_barrier()

// ---------------------------------------------------------------------------
// h[i][c] = [pos, vel] @ W_in + b_in
__global__ __launch_bounds__(256) void embed_kernel(
    const float* __restrict__ pos, const float* __restrict__ vel,
    const float* __restrict__ W, const float* __restrict__ b,
    float* __restrict__ h, int N)
{
    int t = blockIdx.x * blockDim.x + threadIdx.x;
    if (t >= N * 64) return;
    int i = t >> 6, c = t & 63;
    float acc = b[c];
    acc = fmaf(pos[2 * i],     W[c],       acc);
    acc = fmaf(pos[2 * i + 1], W[64 + c],  acc);
    acc = fmaf(vel[2 * i],     W[128 + c], acc);
    acc = fmaf(vel[2 * i + 1], W[192 + c], acc);
    h[t] = acc;
}

// ---------------------------------------------------------------------------
// Edge layer 1: y1[e] = concat(h[dst], h[src]) @ W1 + b1; stats; optional bf16 store.
// Wave per edge; lane = output column; W1 column in 128 VGPRs; x broadcast from a
// wave-private LDS slice (no block barriers needed).
template <bool STORE>
__global__ __launch_bounds__(256) void edge_l1_kernel(
    const float* __restrict__ h,
    const int* __restrict__ di, const int* __restrict__ sj,
    const float* __restrict__ W1, const float* __restrict__ b1,
    float* __restrict__ stats, __hip_bfloat16* __restrict__ y1c, int E)
{
    __shared__ __align__(16) float xs[4][128];
    const int lane = threadIdx.x & 63;
    const int wv   = threadIdx.x >> 6;
    float w[128];
#pragma unroll
    for (int k = 0; k < 128; ++k) w[k] = W1[k * 64 + lane];
    const float bc = b1[lane];
    float s1 = 0.f, s2 = 0.f;
    const int wid = (blockIdx.x * blockDim.x + threadIdx.x) >> 6;
    const int nw  = (gridDim.x * blockDim.x) >> 6;
    for (int e = wid; e < E; e += nw) {
        int ri = di[e], rj = sj[e];
        xs[wv][lane]      = h[(size_t)ri * 64 + lane];
        xs[wv][64 + lane] = h[(size_t)rj * 64 + lane];
        WAVE_BARRIER();
        float a0 = 0.f, a1 = 0.f, a2 = 0.f, a3 = 0.f;
#pragma unroll
        for (int k = 0; k < 32; ++k) {
            a0 = fmaf(xs[wv][k],      w[k],      a0);
            a1 = fmaf(xs[wv][32 + k], w[32 + k], a1);
            a2 = fmaf(xs[wv][64 + k], w[64 + k], a2);
            a3 = fmaf(xs[wv][96 + k], w[96 + k], a3);
        }
        WAVE_BARRIER();
        float acc = bc + ((a0 + a1) + (a2 + a3));
        if (STORE) y1c[(size_t)e * 64 + lane] = __float2bfloat16(acc);
        s1 += acc; s2 += acc * acc;
    }
    atomicAdd(&stats[lane], s1);
    atomicAdd(&stats[64 + lane], s2);
}

// ---------------------------------------------------------------------------
// Edge layers 2(+3): v = y1 (cached or recomputed); r = relu(bn1(v));
// y2 = r @ W2 + b2; then either stats (AGG=false) or relu(bn2(y2)) atomic into
// aggr[dst] (AGG=true).
template <bool HASC, bool AGG>
__global__ __launch_bounds__(256) void edge_l23_kernel(
    const float* __restrict__ h,
    const int* __restrict__ di, const int* __restrict__ sj,
    const float* __restrict__ W1, const float* __restrict__ b1,
    const float* __restrict__ scsh1,
    const float* __restrict__ W2, const float* __restrict__ b2,
    float* __restrict__ stats,
    const __hip_bfloat16* __restrict__ y1c,
    const float* __restrict__ scsh2, float* __restrict__ aggr, int E)
{
    __shared__ __align__(16) float xs[4][128];
    __shared__ __align__(16) float ys[4][64];
    const int lane = threadIdx.x & 63;
    const int wv   = threadIdx.x >> 6;
    float w1r[128];
    if constexpr (!HASC) {
#pragma unroll
        for (int k = 0; k < 128; ++k) w1r[k] = W1[k * 64 + lane];
    }
    float w2r[64];
#pragma unroll
    for (int k = 0; k < 64; ++k) w2r[k] = W2[k * 64 + lane];
    const float bc1 = HASC ? 0.f : b1[lane];
    const float sc1 = scsh1[lane], sh1 = scsh1[64 + lane];
    const float bc2 = b2[lane];
    float sc2 = 0.f, sh2 = 0.f;
    if constexpr (AGG) { sc2 = scsh2[lane]; sh2 = scsh2[64 + lane]; }
    float s1 = 0.f, s2 = 0.f;
    const int wid = (blockIdx.x * blockDim.x + threadIdx.x) >> 6;
    const int nw  = (gridDim.x * blockDim.x) >> 6;
    for (int e = wid; e < E; e += nw) {
        float v;
        if constexpr (HASC) {
            v = __bfloat162float(y1c[(size_t)e * 64 + lane]);
        } else {
            int ri = di[e], rj = sj[e];
            xs[wv][lane]      = h[(size_t)ri * 64 + lane];
            xs[wv][64 + lane] = h[(size_t)rj * 64 + lane];
            WAVE_BARRIER();
            float a0 = 0.f, a1 = 0.f, a2 = 0.f, a3 = 0.f;
#pragma unroll
            for (int k = 0; k < 32; ++k) {
                a0 = fmaf(xs[wv][k],      w1r[k],      a0);
                a1 = fmaf(xs[wv][32 + k], w1r[32 + k], a1);
                a2 = fmaf(xs[wv][64 + k], w1r[64 + k], a2);
                a3 = fmaf(xs[wv][96 + k], w1r[96 + k], a3);
            }
            WAVE_BARRIER();
            v = bc1 + ((a0 + a1) + (a2 + a3));
        }
        float r = fmaxf(fmaf(v, sc1, sh1), 0.f);
        ys[wv][lane] = r;
        WAVE_BARRIER();
        float a0 = 0.f, a1 = 0.f, a2 = 0.f, a3 = 0.f;
#pragma unroll
        for (int k = 0; k < 16; ++k) {
            a0 = fmaf(ys[wv][k],      w2r[k],      a0);
            a1 = fmaf(ys[wv][16 + k], w2r[16 + k], a1);
            a2 = fmaf(ys[wv][32 + k], w2r[32 + k], a2);
            a3 = fmaf(ys[wv][48 + k], w2r[48 + k], a3);
        }
        WAVE_BARRIER();
        float acc = bc2 + ((a0 + a1) + (a2 + a3));
        if constexpr (AGG) {
            float m = fmaxf(fmaf(acc, sc2, sh2), 0.f);
            atomicAdd(&aggr[(size_t)di[e] * 64 + lane], m);
        } else {
            s1 += acc; s2 += acc * acc;
        }
    }
    if constexpr (!AGG) {
        atomicAdd(&stats[lane], s1);
        atomicAdd(&stats[64 + lane], s2);
    }
}

// ---------------------------------------------------------------------------
// Node layer 1 (in place): z = concat(h, aggr) @ W1 + b1 -> overwrites h; stats.
__global__ __launch_bounds__(256) void node_l1_kernel(
    float* __restrict__ h, const float* __restrict__ aggr,
    const float* __restrict__ W1, const float* __restrict__ b1,
    float* __restrict__ stats, int Nn)
{
    __shared__ __align__(16) float xs[4][128];
    const int lane = threadIdx.x & 63;
    const int wv   = threadIdx.x >> 6;
    float w[128];
#pragma unroll
    for (int k = 0; k < 128; ++k) w[k] = W1[k * 64 + lane];
    const float bc = b1[lane];
    float s1 = 0.f, s2 = 0.f;
    const int wid = (blockIdx.x * blockDim.x + threadIdx.x) >> 6;
    const int nw  = (gridDim.x * blockDim.x) >> 6;
    for (int i = wid; i < Nn; i += nw) {
        xs[wv][lane]      = h[(size_t)i * 64 + lane];
        xs[wv][64 + lane] = aggr[(size_t)i * 64 + lane];
        WAVE_BARRIER();
        float a0 = 0.f, a1 = 0.f, a2 = 0.f, a3 = 0.f;
#pragma unroll
        for (int k = 0; k < 32; ++k) {
            a0 = fmaf(xs[wv][k],      w[k],      a0);
            a1 = fmaf(xs[wv][32 + k], w[32 + k], a1);
            a2 = fmaf(xs[wv][64 + k], w[64 + k], a2);
            a3 = fmaf(xs[wv][96 + k], w[96 + k], a3);
        }
        WAVE_BARRIER();
        float acc = bc + ((a0 + a1) + (a2 + a3));
        h[(size_t)i * 64 + lane] = acc;   // row-local in-place
        s1 += acc; s2 += acc * acc;
    }
    atomicAdd(&stats[lane], s1);
    atomicAdd(&stats[64 + lane], s2);
}

// ---------------------------------------------------------------------------
// Node layer 2 (in place): t = relu(bn3(z)) @ W2 + b2 -> overwrites h; stats.
__global__ __launch_bounds__(256) void node_l2_kernel(
    float* __restrict__ h, const float* __restrict__ scsh,
    const float* __restrict__ W2, const float* __restrict__ b2,
    float* __restrict__ stats, int Nn)
{
    __shared__ __align__(16) float ys[4][64];
    const int lane = threadIdx.x & 63;
    const int wv   = threadIdx.x >> 6;
    float w[64];
#pragma unroll
    for (int k = 0; k < 64; ++k) w[k] = W2[k * 64 + lane];
    const float bc = b2[lane];
    const float sc = scsh[lane], sh = scsh[64 + lane];
    float s1 = 0.f, s2 = 0.f;
    const int wid = (blockIdx.x * blockDim.x + threadIdx.x) >> 6;
    const int nw  = (gridDim.x * blockDim.x) >> 6;
    for (int i = wid; i < Nn; i += nw) {
        float v = h[(size_t)i * 64 + lane];
        ys[wv][lane] = fmaxf(fmaf(v, sc, sh), 0.f);
        WAVE_BARRIER();
        float a0 = 0.f, a1 = 0.f, a2 = 0.f, a3 = 0.f;
#pragma unroll
        for (int k = 0; k < 16; ++k) {
            a0 = fmaf(ys[wv][k],      w[k],      a0);
            a1 = fmaf(ys[wv][16 + k], w[16 + k], a1);
            a2 = fmaf(ys[wv][32 + k], w[32 + k], a2);
            a3 = fmaf(ys[wv][48 + k], w[48 + k], a3);
        }
        WAVE_BARRIER();
        float acc = bc + ((a0 + a1) + (a2 + a3));
        h[(size_t)i * 64 + lane] = acc;
        s1 += acc; s2 += acc * acc;
    }
    atomicAdd(&stats[lane], s1);
    atomicAdd(&stats[64 + lane], s2);
}

// ---------------------------------------------------------------------------
__global__ void finalize_kernel(const float* __restrict__ raw,
                                const float* __restrict__ gamma,
                                const float* __restrict__ beta,
                                float* __restrict__ scsh, float inv_cnt)
{
    int c = threadIdx.x;
    float mu  = raw[c] * inv_cnt;
    float var = fmaf(raw[64 + c], inv_cnt, -mu * mu);
    float rs  = rsqrtf(var + BN_EPS);
    float sc  = rs * gamma[c];
    scsh[c]      = sc;
    scsh[64 + c] = fmaf(-mu, sc, beta[c]);
}

// ---------------------------------------------------------------------------
// out[i] = relu(bn4(t[i])) . Wp + bp
__global__ __launch_bounds__(256) void pred_kernel(
    const float* __restrict__ t, const float* __restrict__ scsh,
    const float* __restrict__ Wp, const float* __restrict__ bp,
    float* __restrict__ out, int Nn)
{
    const int lane = threadIdx.x & 63;
    const float sc = scsh[lane], sh = scsh[64 + lane];
    const float wc = Wp[lane];
    const float bb = bp[0];
    const int wid = (blockIdx.x * blockDim.x + threadIdx.x) >> 6;
    const int nw  = (gridDim.x * blockDim.x) >> 6;
    for (int i = wid; i < Nn; i += nw) {
        float v = t[(size_t)i * 64 + lane];
        float p = fmaxf(fmaf(v, sc, sh), 0.f) * wc;
#pragma unroll
        for (int off = 32; off > 0; off >>= 1) p += __shfl_xor(p, off, 64);
        if (lane == 0) out[i] = p + bb;
    }
}

// ---------------------------------------------------------------------------
extern "C" void kernel_launch(void* const* d_in, const int* in_sizes, int n_in,
                              void* d_out, int out_size, void* d_ws, size_t ws_size,
                              hipStream_t stream)
{
    const float* pos  = (const float*)d_in[0];
    const float* vel  = (const float*)d_in[1];
    const int*   eidx = (const int*)d_in[2];
    const float* W_in = (const float*)d_in[3];
    const float* b_in = (const float*)d_in[4];
    const float* mW1  = (const float*)d_in[5];
    const float* mb1  = (const float*)d_in[6];
    const float* mg1  = (const float*)d_in[7];
    const float* mB1  = (const float*)d_in[8];
    const float* mW2  = (const float*)d_in[9];
    const float* mb2  = (const float*)d_in[10];
    const float* mg2  = (const float*)d_in[11];
    const float* mB2  = (const float*)d_in[12];
    const float* uW1  = (const float*)d_in[13];
    const float* ub1  = (const float*)d_in[14];
    const float* ug1  = (const float*)d_in[15];
    const float* uB1  = (const float*)d_in[16];
    const float* uW2  = (const float*)d_in[17];
    const float* ub2  = (const float*)d_in[18];
    const float* ug2  = (const float*)d_in[19];
    const float* uB2  = (const float*)d_in[20];
    const float* Wp   = (const float*)d_in[21];
    const float* bp   = (const float*)d_in[22];

    const int N = in_sizes[0] / 2;
    const int E = in_sizes[2] / 2;
    const int* src = eidx;       // edge_index[0] = source j
    const int* dst = eidx + E;   // edge_index[1] = dest   i (aggregation target)

    float* ws    = (float*)d_ws;
    float* stats = ws;                      // 4 stages x 128 (sum, sumsq)
    float* scsh  = ws + 512;                // 4 stages x 128 (scale, shift)
    float* h     = ws + 1024;               // N*64 (reused in place for z, t)
    float* aggr  = h + (size_t)N * 64;      // N*64
    __hip_bfloat16* y1c = (__hip_bfloat16*)(aggr + (size_t)N * 64);
    float* out   = (float*)d_out;

    const size_t need_base  = (1024 + 2 * (size_t)N * 64) * sizeof(float);
    const size_t need_cache = need_base + (size_t)E * 64 * sizeof(__hip_bfloat16);
    const bool use_cache = ws_size >= need_cache;

    hipMemsetAsync(stats, 0, 512 * sizeof(float), stream);
    hipMemsetAsync(aggr, 0, (size_t)N * 64 * sizeof(float), stream);

    embed_kernel<<<(N * 64 + 255) / 256, 256, 0, stream>>>(pos, vel, W_in, b_in, h, N);

    if (use_cache)
        edge_l1_kernel<true><<<4096, 256, 0, stream>>>(h, dst, src, mW1, mb1, stats + 0, y1c, E);
    else
        edge_l1_kernel<false><<<4096, 256, 0, stream>>>(h, dst, src, mW1, mb1, stats + 0, nullptr, E);
    finalize_kernel<<<1, 64, 0, stream>>>(stats + 0, mg1, mB1, scsh + 0, 1.0f / (float)E);

    if (use_cache)
        edge_l23_kernel<true, false><<<4096, 256, 0, stream>>>(
            h, dst, src, mW1, mb1, scsh + 0, mW2, mb2, stats + 128, y1c, nullptr, nullptr, E);
    else
        edge_l23_kernel<false, false><<<4096, 256, 0, stream>>>(
            h, dst, src, mW1, mb1, scsh + 0, mW2, mb2, stats + 128, nullptr, nullptr, nullptr, E);
    finalize_kernel<<<1, 64, 0, stream>>>(stats + 128, mg2, mB2, scsh + 128, 1.0f / (float)E);

    if (use_cache)
        edge_l23_kernel<true, true><<<4096, 256, 0, stream>>>(
            h, dst, src, mW1, mb1, scsh + 0, mW2, mb2, nullptr, y1c, scsh + 128, aggr, E);
    else
        edge_l23_kernel<false, true><<<4096, 256, 0, stream>>>(
            h, dst, src, mW1, mb1, scsh + 0, mW2, mb2, nullptr, nullptr, scsh + 128, aggr, E);

    node_l1_kernel<<<1024, 256, 0, stream>>>(h, aggr, uW1, ub1, stats + 256, N);
    finalize_kernel<<<1, 64, 0, stream>>>(stats + 256, ug1, uB1, scsh + 256, 1.0f / (float)N);
    node_l2_kernel<<<1024, 256, 0, stream>>>(h, scsh + 256, uW2, ub2, stats + 384, N);
    finalize_kernel<<<1, 64, 0, stream>>>(stats + 384, ug2, uB2, scsh + 384, 1.0f / (float)N);
    pred_kernel<<<512, 256, 0, stream>>>(h, scsh + 384, Wp, bp, out, N);
}

// Round 3
// 1619.851 us; speedup vs baseline: 1.5047x; 1.5047x over previous
//
#include <hip/hip_runtime.h>
#include <hip/hip_bf16.h>

#define BN_EPS 1e-5f

typedef short short8 __attribute__((ext_vector_type(8)));
typedef float f32x4  __attribute__((ext_vector_type(4)));

__device__ inline float bf2f(short s) {
    unsigned u = ((unsigned)(unsigned short)s) << 16;
    return __builtin_bit_cast(float, u);
}
__device__ inline short f2bf(float f) {
    __hip_bfloat16 h = __float2bfloat16(f);
    return __builtin_bit_cast(short, h);
}
__device__ inline f32x4 mfma16(short8 a, short8 b, f32x4 c) {
    return __builtin_amdgcn_mfma_f32_16x16x32_bf16(a, b, c, 0, 0, 0);
}

// ---------------------------------------------------------------------------
// Pre-transpose weights [K][64] fp32 into per-lane MFMA B-fragments (bf16):
// frag slot s = (t*4+cb)*64 + lane holds 8 bf16: W[t*32+(lane>>4)*8+j][cb*16+(lane&15)]
__global__ void prep_bfrag_kernel(const float* __restrict__ W, short* __restrict__ out, int K)
{
    int nt = K >> 5;
    int total = nt * 4 * 64;
    for (int s = blockIdx.x * blockDim.x + threadIdx.x; s < total; s += gridDim.x * blockDim.x) {
        int lane = s & 63, cb = (s >> 6) & 3, t = s >> 8;
        int n  = cb * 16 + (lane & 15);
        int k0 = t * 32 + ((lane >> 4) * 8);
        short8 v;
#pragma unroll
        for (int j = 0; j < 8; ++j) v[j] = f2bf(W[(k0 + j) * 64 + n]);
        *(short8*)(out + (size_t)s * 8) = v;
    }
}

// ---------------------------------------------------------------------------
// h2[i][c] = bf16([pos, vel] @ W_in + b_in)
__global__ __launch_bounds__(256) void embed_kernel(
    const float* __restrict__ pos, const float* __restrict__ vel,
    const float* __restrict__ W, const float* __restrict__ b,
    short* __restrict__ h2, int N)
{
    int t = blockIdx.x * blockDim.x + threadIdx.x;
    if (t >= N * 64) return;
    int i = t >> 6, c = t & 63;
    float acc = b[c];
    acc = fmaf(pos[2 * i],     W[c],       acc);
    acc = fmaf(pos[2 * i + 1], W[64 + c],  acc);
    acc = fmaf(vel[2 * i],     W[128 + c], acc);
    acc = fmaf(vel[2 * i + 1], W[192 + c], acc);
    h2[t] = f2bf(acc);
}

// ---------------------------------------------------------------------------
// P1: y1[e] = bf16(concat(h2[di[e]], h2[sj[e]]) @ W1 + b1); col stats (fp32).
// Wave-per-16-edge tile; A gathered straight from global in fragment layout.
__global__ __launch_bounds__(256) void edge_p1_mfma(
    const short* __restrict__ h2, const int* __restrict__ di, const int* __restrict__ sj,
    const short* __restrict__ w1f, const float* __restrict__ b1,
    short* __restrict__ y1, float* __restrict__ stats, int E)
{
    const int lane = threadIdx.x & 63;
    const int wid  = (blockIdx.x * blockDim.x + threadIdx.x) >> 6;
    const int nw   = (gridDim.x * blockDim.x) >> 6;
    short8 bf[4][4];
#pragma unroll
    for (int t = 0; t < 4; ++t)
#pragma unroll
        for (int cb = 0; cb < 4; ++cb)
            bf[t][cb] = *(const short8*)(w1f + ((size_t)(t * 4 + cb) * 64 + lane) * 8);
    const int m  = lane & 15;
    const int ko = (lane >> 4) * 8;
    const int row0 = (lane >> 4) * 4;
    float bc[4];
#pragma unroll
    for (int cb = 0; cb < 4; ++cb) bc[cb] = b1[cb * 16 + m];
    float s1[4] = {0.f, 0.f, 0.f, 0.f}, s2[4] = {0.f, 0.f, 0.f, 0.f};
    const int ntiles = E >> 4;
    for (int tile = wid; tile < ntiles; tile += nw) {
        int e  = tile * 16 + m;
        int ri = di[e], rj = sj[e];
        const short* rd = h2 + (size_t)ri * 64;
        const short* rs = h2 + (size_t)rj * 64;
        short8 a0 = *(const short8*)(rd + ko);
        short8 a1 = *(const short8*)(rd + 32 + ko);
        short8 a2 = *(const short8*)(rs + ko);
        short8 a3 = *(const short8*)(rs + 32 + ko);
#pragma unroll
        for (int cb = 0; cb < 4; ++cb) {
            f32x4 c = {0.f, 0.f, 0.f, 0.f};
            c = mfma16(a0, bf[0][cb], c);
            c = mfma16(a1, bf[1][cb], c);
            c = mfma16(a2, bf[2][cb], c);
            c = mfma16(a3, bf[3][cb], c);
            size_t base = ((size_t)(tile * 16 + row0)) * 64 + cb * 16 + m;
#pragma unroll
            for (int r = 0; r < 4; ++r) {
                float v = c[r] + bc[cb];
                y1[base + (size_t)r * 64] = f2bf(v);
                s1[cb] += v; s2[cb] += v * v;
            }
        }
    }
#pragma unroll
    for (int cb = 0; cb < 4; ++cb) {
        float a = s1[cb], b = s2[cb];
        a += __shfl_xor(a, 16, 64); a += __shfl_xor(a, 32, 64);
        b += __shfl_xor(b, 16, 64); b += __shfl_xor(b, 32, 64);
        if (lane < 16) {
            atomicAdd(&stats[cb * 16 + lane], a);
            atomicAdd(&stats[64 + cb * 16 + lane], b);
        }
    }
}

// ---------------------------------------------------------------------------
// P2: y[e] = bf16(relu(bn1(y[e])) @ W2 + b2), in place over y1; col stats.
__global__ __launch_bounds__(256) void edge_p2_mfma(
    short* __restrict__ y, const float* __restrict__ scsh1,
    const short* __restrict__ w2f, const float* __restrict__ b2,
    float* __restrict__ stats, int E)
{
    const int lane = threadIdx.x & 63;
    const int wid  = (blockIdx.x * blockDim.x + threadIdx.x) >> 6;
    const int nw   = (gridDim.x * blockDim.x) >> 6;
    short8 bf[2][4];
#pragma unroll
    for (int t = 0; t < 2; ++t)
#pragma unroll
        for (int cb = 0; cb < 4; ++cb)
            bf[t][cb] = *(const short8*)(w2f + ((size_t)(t * 4 + cb) * 64 + lane) * 8);
    const int m  = lane & 15;
    const int ko = (lane >> 4) * 8;
    const int row0 = (lane >> 4) * 4;
    float bc[4];
#pragma unroll
    for (int cb = 0; cb < 4; ++cb) bc[cb] = b2[cb * 16 + m];
    float sck[16], shk[16];
#pragma unroll
    for (int t = 0; t < 2; ++t)
#pragma unroll
        for (int j = 0; j < 8; ++j) {
            int k = t * 32 + ko + j;
            sck[t * 8 + j] = scsh1[k];
            shk[t * 8 + j] = scsh1[64 + k];
        }
    float s1[4] = {0.f, 0.f, 0.f, 0.f}, s2[4] = {0.f, 0.f, 0.f, 0.f};
    const int ntiles = E >> 4;
    for (int tile = wid; tile < ntiles; tile += nw) {
        int e = tile * 16 + m;
        const short* row = y + (size_t)e * 64;
        short8 r0 = *(const short8*)(row + ko);
        short8 r1 = *(const short8*)(row + 32 + ko);
        short8 a0, a1;
#pragma unroll
        for (int j = 0; j < 8; ++j) {
            a0[j] = f2bf(fmaxf(fmaf(bf2f(r0[j]), sck[j],     shk[j]),     0.f));
            a1[j] = f2bf(fmaxf(fmaf(bf2f(r1[j]), sck[8 + j], shk[8 + j]), 0.f));
        }
#pragma unroll
        for (int cb = 0; cb < 4; ++cb) {
            f32x4 c = {0.f, 0.f, 0.f, 0.f};
            c = mfma16(a0, bf[0][cb], c);
            c = mfma16(a1, bf[1][cb], c);
            size_t base = ((size_t)(tile * 16 + row0)) * 64 + cb * 16 + m;
#pragma unroll
            for (int r = 0; r < 4; ++r) {
                float v = c[r] + bc[cb];
                y[base + (size_t)r * 64] = f2bf(v);
                s1[cb] += v; s2[cb] += v * v;
            }
        }
    }
#pragma unroll
    for (int cb = 0; cb < 4; ++cb) {
        float a = s1[cb], b = s2[cb];
        a += __shfl_xor(a, 16, 64); a += __shfl_xor(a, 32, 64);
        b += __shfl_xor(b, 16, 64); b += __shfl_xor(b, 32, 64);
        if (lane < 16) {
            atomicAdd(&stats[cb * 16 + lane], a);
            atomicAdd(&stats[64 + cb * 16 + lane], b);
        }
    }
}

// ---------------------------------------------------------------------------
// P3: aggr[di[e]][c] += relu(bn2(y2[e][c])).  Thread = (edge, col-pair).
__global__ __launch_bounds__(256) void agg_kernel(
    const short* __restrict__ y2, const int* __restrict__ di,
    const float* __restrict__ scsh2, float* __restrict__ aggr, int E)
{
    const int tid    = blockIdx.x * blockDim.x + threadIdx.x;
    const int stride = gridDim.x * blockDim.x;      // multiple of 32
    const int c2 = tid & 31;
    const int c0 = c2 * 2;
    const float sa = scsh2[c0],     ha = scsh2[64 + c0];
    const float sb = scsh2[c0 + 1], hb = scsh2[64 + c0 + 1];
    const int total = E * 32;
    for (int t = tid; t < total; t += stride) {
        int e = t >> 5;
        unsigned u = *(const unsigned*)(y2 + (size_t)e * 64 + c0);
        float m0 = fmaxf(fmaf(bf2f((short)(u & 0xffff)), sa, ha), 0.f);
        float m1 = fmaxf(fmaf(bf2f((short)(u >> 16)),    sb, hb), 0.f);
        float* d = aggr + (size_t)di[e] * 64 + c0;
        atomicAdd(d, m0);
        atomicAdd(d + 1, m1);
    }
}

// ---------------------------------------------------------------------------
__global__ void finalize_kernel(const float* __restrict__ raw,
                                const float* __restrict__ gamma,
                                const float* __restrict__ beta,
                                float* __restrict__ scsh, float inv_cnt)
{
    int c = threadIdx.x;
    float mu  = raw[c] * inv_cnt;
    float var = fmaf(raw[64 + c], inv_cnt, -mu * mu);
    float rs  = rsqrtf(var + BN_EPS);
    float sc  = rs * gamma[c];
    scsh[c]      = sc;
    scsh[64 + c] = fmaf(-mu, sc, beta[c]);
}

// ---------------------------------------------------------------------------
// Node layer 1: z = concat(bf16 h2, fp32 aggr) @ W1 + b1 -> overwrites z(=aggr); stats.
__global__ __launch_bounds__(256) void node_l1_kernel(
    const short* __restrict__ h2, float* __restrict__ z,
    const float* __restrict__ W1, const float* __restrict__ b1,
    float* __restrict__ stats, int Nn)
{
    __shared__ __align__(16) float xs[4][128];
    const int lane = threadIdx.x & 63;
    const int wv   = threadIdx.x >> 6;
    float w[128];
#pragma unroll
    for (int k = 0; k < 128; ++k) w[k] = W1[k * 64 + lane];
    const float bc = b1[lane];
    float s1 = 0.f, s2 = 0.f;
    const int wid = (blockIdx.x * blockDim.x + threadIdx.x) >> 6;
    const int nw  = (gridDim.x * blockDim.x) >> 6;
    for (int i = wid; i < Nn; i += nw) {
        xs[wv][lane]      = bf2f(h2[(size_t)i * 64 + lane]);
        xs[wv][64 + lane] = z[(size_t)i * 64 + lane];
        __builtin_amdgcn_wave_barrier();
        float a0 = 0.f, a1 = 0.f, a2 = 0.f, a3 = 0.f;
#pragma unroll
        for (int k = 0; k < 32; ++k) {
            a0 = fmaf(xs[wv][k],      w[k],      a0);
            a1 = fmaf(xs[wv][32 + k], w[32 + k], a1);
            a2 = fmaf(xs[wv][64 + k], w[64 + k], a2);
            a3 = fmaf(xs[wv][96 + k], w[96 + k], a3);
        }
        __builtin_amdgcn_wave_barrier();
        float acc = bc + ((a0 + a1) + (a2 + a3));
        z[(size_t)i * 64 + lane] = acc;     // row-local in-place
        s1 += acc; s2 += acc * acc;
    }
    atomicAdd(&stats[lane], s1);
    atomicAdd(&stats[64 + lane], s2);
}

// ---------------------------------------------------------------------------
// Node layer 2 (in place over z): t = relu(bn3(z)) @ W2 + b2; stats.
__global__ __launch_bounds__(256) void node_l2_kernel(
    float* __restrict__ z, const float* __restrict__ scsh,
    const float* __restrict__ W2, const float* __restrict__ b2,
    float* __restrict__ stats, int Nn)
{
    __shared__ __align__(16) float ys[4][64];
    const int lane = threadIdx.x & 63;
    const int wv   = threadIdx.x >> 6;
    float w[64];
#pragma unroll
    for (int k = 0; k < 64; ++k) w[k] = W2[k * 64 + lane];
    const float bc = b2[lane];
    const float sc = scsh[lane], sh = scsh[64 + lane];
    float s1 = 0.f, s2 = 0.f;
    const int wid = (blockIdx.x * blockDim.x + threadIdx.x) >> 6;
    const int nw  = (gridDim.x * blockDim.x) >> 6;
    for (int i = wid; i < Nn; i += nw) {
        float v = z[(size_t)i * 64 + lane];
        ys[wv][lane] = fmaxf(fmaf(v, sc, sh), 0.f);
        __builtin_amdgcn_wave_barrier();
        float a0 = 0.f, a1 = 0.f, a2 = 0.f, a3 = 0.f;
#pragma unroll
        for (int k = 0; k < 16; ++k) {
            a0 = fmaf(ys[wv][k],      w[k],      a0);
            a1 = fmaf(ys[wv][16 + k], w[16 + k], a1);
            a2 = fmaf(ys[wv][32 + k], w[32 + k], a2);
            a3 = fmaf(ys[wv][48 + k], w[48 + k], a3);
        }
        __builtin_amdgcn_wave_barrier();
        float acc = bc + ((a0 + a1) + (a2 + a3));
        z[(size_t)i * 64 + lane] = acc;
        s1 += acc; s2 += acc * acc;
    }
    atomicAdd(&stats[lane], s1);
    atomicAdd(&stats[64 + lane], s2);
}

// ---------------------------------------------------------------------------
// out[i] = relu(bn4(t[i])) . Wp + bp
__global__ __launch_bounds__(256) void pred_kernel(
    const float* __restrict__ t, const float* __restrict__ scsh,
    const float* __restrict__ Wp, const float* __restrict__ bp,
    float* __restrict__ out, int Nn)
{
    const int lane = threadIdx.x & 63;
    const float sc = scsh[lane], sh = scsh[64 + lane];
    const float wc = Wp[lane];
    const float bb = bp[0];
    const int wid = (blockIdx.x * blockDim.x + threadIdx.x) >> 6;
    const int nw  = (gridDim.x * blockDim.x) >> 6;
    for (int i = wid; i < Nn; i += nw) {
        float v = t[(size_t)i * 64 + lane];
        float p = fmaxf(fmaf(v, sc, sh), 0.f) * wc;
#pragma unroll
        for (int off = 32; off > 0; off >>= 1) p += __shfl_xor(p, off, 64);
        if (lane == 0) out[i] = p + bb;
    }
}

// ---------------------------------------------------------------------------
extern "C" void kernel_launch(void* const* d_in, const int* in_sizes, int n_in,
                              void* d_out, int out_size, void* d_ws, size_t ws_size,
                              hipStream_t stream)
{
    const float* pos  = (const float*)d_in[0];
    const float* vel  = (const float*)d_in[1];
    const int*   eidx = (const int*)d_in[2];
    const float* W_in = (const float*)d_in[3];
    const float* b_in = (const float*)d_in[4];
    const float* mW1  = (const float*)d_in[5];
    const float* mb1  = (const float*)d_in[6];
    const float* mg1  = (const float*)d_in[7];
    const float* mB1  = (const float*)d_in[8];
    const float* mW2  = (const float*)d_in[9];
    const float* mb2  = (const float*)d_in[10];
    const float* mg2  = (const float*)d_in[11];
    const float* mB2  = (const float*)d_in[12];
    const float* uW1  = (const float*)d_in[13];
    const float* ub1  = (const float*)d_in[14];
    const float* ug1  = (const float*)d_in[15];
    const float* uB1  = (const float*)d_in[16];
    const float* uW2  = (const float*)d_in[17];
    const float* ub2  = (const float*)d_in[18];
    const float* ug2  = (const float*)d_in[19];
    const float* uB2  = (const float*)d_in[20];
    const float* Wp   = (const float*)d_in[21];
    const float* bp   = (const float*)d_in[22];

    const int N = in_sizes[0] / 2;
    const int E = in_sizes[2] / 2;
    const int* src = eidx;       // edge_index[0] = source j
    const int* dst = eidx + E;   // edge_index[1] = dest   i (aggregation target)

    // workspace layout (≈243 MB total)
    float* ws    = (float*)d_ws;
    float* stats = ws;                       // 4 stages x 128 (sum, sumsq)
    float* scsh  = ws + 512;                 // 4 stages x 128 (scale, shift)
    short* w1f   = (short*)(ws + 1024);      // 8192 shorts (16 B-frag slots x 64 lanes x 8)
    short* w2f   = w1f + 8192;               // 4096 shorts
    short* h2    = w2f + 4096;               // N*64 bf16   (16B-aligned: byte 28672)
    float* aggr  = (float*)(h2 + (size_t)N * 64);   // N*64 fp32 (reused as z, t)
    short* y1    = (short*)(aggr + (size_t)N * 64); // E*64 bf16 (y1, then y2 in place)
    float* out   = (float*)d_out;

    hipMemsetAsync(stats, 0, 512 * sizeof(float), stream);
    hipMemsetAsync(aggr, 0, (size_t)N * 64 * sizeof(float), stream);

    prep_bfrag_kernel<<<4, 256, 0, stream>>>(mW1, w1f, 128);
    prep_bfrag_kernel<<<2, 256, 0, stream>>>(mW2, w2f, 64);

    embed_kernel<<<(N * 64 + 255) / 256, 256, 0, stream>>>(pos, vel, W_in, b_in, h2, N);

    edge_p1_mfma<<<2048, 256, 0, stream>>>(h2, dst, src, w1f, mb1, y1, stats + 0, E);
    finalize_kernel<<<1, 64, 0, stream>>>(stats + 0, mg1, mB1, scsh + 0, 1.0f / (float)E);

    edge_p2_mfma<<<2048, 256, 0, stream>>>(y1, scsh + 0, w2f, mb2, stats + 128, E);
    finalize_kernel<<<1, 64, 0, stream>>>(stats + 128, mg2, mB2, scsh + 128, 1.0f / (float)E);

    agg_kernel<<<8192, 256, 0, stream>>>(y1, dst, scsh + 128, aggr, E);

    node_l1_kernel<<<2048, 256, 0, stream>>>(h2, aggr, uW1, ub1, stats + 256, N);
    finalize_kernel<<<1, 64, 0, stream>>>(stats + 256, ug1, uB1, scsh + 256, 1.0f / (float)N);
    node_l2_kernel<<<1024, 256, 0, stream>>>(aggr, scsh + 256, uW2, ub2, stats + 384, N);
    finalize_kernel<<<1, 64, 0, stream>>>(stats + 384, ug2, uB2, scsh + 384, 1.0f / (float)N);
    pred_kernel<<<512, 256, 0, stream>>>(aggr, scsh + 384, Wp, bp, out, N);
}

// Round 4
// 1251.101 us; speedup vs baseline: 1.9482x; 1.2947x over previous
//
#include <hip/hip_runtime.h>
#include <hip/hip_bf16.h>

#define BN_EPS 1e-5f

typedef short short8 __attribute__((ext_vector_type(8)));
typedef float f32x4  __attribute__((ext_vector_type(4)));

__device__ inline float bf2f(short s) {
    unsigned u = ((unsigned)(unsigned short)s) << 16;
    return __builtin_bit_cast(float, u);
}
__device__ inline short f2bf(float f) {
    __hip_bfloat16 h = __float2bfloat16(f);
    return __builtin_bit_cast(short, h);
}
__device__ inline f32x4 mfma16(short8 a, short8 b, f32x4 c) {
    return __builtin_amdgcn_mfma_f32_16x16x32_bf16(a, b, c, 0, 0, 0);
}

// ---------------------------------------------------------------------------
// Pre-transpose weights [K][64] fp32 into per-lane MFMA B-fragments (bf16).
__global__ void prep_bfrag_kernel(const float* __restrict__ W, short* __restrict__ out, int K)
{
    int nt = K >> 5;
    int total = nt * 4 * 64;
    for (int s = blockIdx.x * blockDim.x + threadIdx.x; s < total; s += gridDim.x * blockDim.x) {
        int lane = s & 63, cb = (s >> 6) & 3, t = s >> 8;
        int n  = cb * 16 + (lane & 15);
        int k0 = t * 32 + ((lane >> 4) * 8);
        short8 v;
#pragma unroll
        for (int j = 0; j < 8; ++j) v[j] = f2bf(W[(k0 + j) * 64 + n]);
        *(short8*)(out + (size_t)s * 8) = v;
    }
}

// ---------------------------------------------------------------------------
// h2[i][c] = bf16([pos, vel] @ W_in + b_in)
__global__ __launch_bounds__(256) void embed_kernel(
    const float* __restrict__ pos, const float* __restrict__ vel,
    const float* __restrict__ W, const float* __restrict__ b,
    short* __restrict__ h2, int N)
{
    int t = blockIdx.x * blockDim.x + threadIdx.x;
    if (t >= N * 64) return;
    int i = t >> 6, c = t & 63;
    float acc = b[c];
    acc = fmaf(pos[2 * i],     W[c],       acc);
    acc = fmaf(pos[2 * i + 1], W[64 + c],  acc);
    acc = fmaf(vel[2 * i],     W[128 + c], acc);
    acc = fmaf(vel[2 * i + 1], W[192 + c], acc);
    h2[t] = f2bf(acc);
}

// ---------------------------------------------------------------------------
// P1: y1[e] = bf16(concat(h2[di[e]], h2[sj[e]]) @ W1 + b1); col stats (fp32).
__global__ __launch_bounds__(256) void edge_p1_mfma(
    const short* __restrict__ h2, const int* __restrict__ di, const int* __restrict__ sj,
    const short* __restrict__ w1f, const float* __restrict__ b1,
    short* __restrict__ y1, float* __restrict__ stats, int E)
{
    const int lane = threadIdx.x & 63;
    const int wid  = (blockIdx.x * blockDim.x + threadIdx.x) >> 6;
    const int nw   = (gridDim.x * blockDim.x) >> 6;
    short8 bf[4][4];
#pragma unroll
    for (int t = 0; t < 4; ++t)
#pragma unroll
        for (int cb = 0; cb < 4; ++cb)
            bf[t][cb] = *(const short8*)(w1f + ((size_t)(t * 4 + cb) * 64 + lane) * 8);
    const int m  = lane & 15;
    const int ko = (lane >> 4) * 8;
    const int row0 = (lane >> 4) * 4;
    float bc[4];
#pragma unroll
    for (int cb = 0; cb < 4; ++cb) bc[cb] = b1[cb * 16 + m];
    float s1[4] = {0.f, 0.f, 0.f, 0.f}, s2[4] = {0.f, 0.f, 0.f, 0.f};
    const int ntiles = E >> 4;
    for (int tile = wid; tile < ntiles; tile += nw) {
        int e  = tile * 16 + m;
        int ri = di[e], rj = sj[e];
        const short* rd = h2 + (size_t)ri * 64;
        const short* rs = h2 + (size_t)rj * 64;
        short8 a0 = *(const short8*)(rd + ko);
        short8 a1 = *(const short8*)(rd + 32 + ko);
        short8 a2 = *(const short8*)(rs + ko);
        short8 a3 = *(const short8*)(rs + 32 + ko);
#pragma unroll
        for (int cb = 0; cb < 4; ++cb) {
            f32x4 c = {0.f, 0.f, 0.f, 0.f};
            c = mfma16(a0, bf[0][cb], c);
            c = mfma16(a1, bf[1][cb], c);
            c = mfma16(a2, bf[2][cb], c);
            c = mfma16(a3, bf[3][cb], c);
            size_t base = ((size_t)(tile * 16 + row0)) * 64 + cb * 16 + m;
#pragma unroll
            for (int r = 0; r < 4; ++r) {
                float v = c[r] + bc[cb];
                y1[base + (size_t)r * 64] = f2bf(v);
                s1[cb] += v; s2[cb] += v * v;
            }
        }
    }
#pragma unroll
    for (int cb = 0; cb < 4; ++cb) {
        float a = s1[cb], b = s2[cb];
        a += __shfl_xor(a, 16, 64); a += __shfl_xor(a, 32, 64);
        b += __shfl_xor(b, 16, 64); b += __shfl_xor(b, 32, 64);
        if (lane < 16) {
            atomicAdd(&stats[cb * 16 + lane], a);
            atomicAdd(&stats[64 + cb * 16 + lane], b);
        }
    }
}

// ---------------------------------------------------------------------------
// P2: y[e] = bf16(relu(bn1(y[e])) @ W2 + b2), in place; col stats.
__global__ __launch_bounds__(256) void edge_p2_mfma(
    short* __restrict__ y, const float* __restrict__ scsh1,
    const short* __restrict__ w2f, const float* __restrict__ b2,
    float* __restrict__ stats, int E)
{
    const int lane = threadIdx.x & 63;
    const int wid  = (blockIdx.x * blockDim.x + threadIdx.x) >> 6;
    const int nw   = (gridDim.x * blockDim.x) >> 6;
    short8 bf[2][4];
#pragma unroll
    for (int t = 0; t < 2; ++t)
#pragma unroll
        for (int cb = 0; cb < 4; ++cb)
            bf[t][cb] = *(const short8*)(w2f + ((size_t)(t * 4 + cb) * 64 + lane) * 8);
    const int m  = lane & 15;
    const int ko = (lane >> 4) * 8;
    const int row0 = (lane >> 4) * 4;
    float bc[4];
#pragma unroll
    for (int cb = 0; cb < 4; ++cb) bc[cb] = b2[cb * 16 + m];
    float sck[16], shk[16];
#pragma unroll
    for (int t = 0; t < 2; ++t)
#pragma unroll
        for (int j = 0; j < 8; ++j) {
            int k = t * 32 + ko + j;
            sck[t * 8 + j] = scsh1[k];
            shk[t * 8 + j] = scsh1[64 + k];
        }
    float s1[4] = {0.f, 0.f, 0.f, 0.f}, s2[4] = {0.f, 0.f, 0.f, 0.f};
    const int ntiles = E >> 4;
    for (int tile = wid; tile < ntiles; tile += nw) {
        int e = tile * 16 + m;
        const short* row = y + (size_t)e * 64;
        short8 r0 = *(const short8*)(row + ko);
        short8 r1 = *(const short8*)(row + 32 + ko);
        short8 a0, a1;
#pragma unroll
        for (int j = 0; j < 8; ++j) {
            a0[j] = f2bf(fmaxf(fmaf(bf2f(r0[j]), sck[j],     shk[j]),     0.f));
            a1[j] = f2bf(fmaxf(fmaf(bf2f(r1[j]), sck[8 + j], shk[8 + j]), 0.f));
        }
#pragma unroll
        for (int cb = 0; cb < 4; ++cb) {
            f32x4 c = {0.f, 0.f, 0.f, 0.f};
            c = mfma16(a0, bf[0][cb], c);
            c = mfma16(a1, bf[1][cb], c);
            size_t base = ((size_t)(tile * 16 + row0)) * 64 + cb * 16 + m;
#pragma unroll
            for (int r = 0; r < 4; ++r) {
                float v = c[r] + bc[cb];
                y[base + (size_t)r * 64] = f2bf(v);
                s1[cb] += v; s2[cb] += v * v;
            }
        }
    }
#pragma unroll
    for (int cb = 0; cb < 4; ++cb) {
        float a = s1[cb], b = s2[cb];
        a += __shfl_xor(a, 16, 64); a += __shfl_xor(a, 32, 64);
        b += __shfl_xor(b, 16, 64); b += __shfl_xor(b, 32, 64);
        if (lane < 16) {
            atomicAdd(&stats[cb * 16 + lane], a);
            atomicAdd(&stats[64 + cb * 16 + lane], b);
        }
    }
}

// ---------------------------------------------------------------------------
// Counting-sort by dst: hist -> scan (3 kernels) -> slot scatter.
__global__ __launch_bounds__(256) void hist_kernel(
    const int* __restrict__ di, int* __restrict__ cnt, int E)
{
    for (int e = blockIdx.x * blockDim.x + threadIdx.x; e < E; e += gridDim.x * blockDim.x)
        atomicAdd(&cnt[di[e]], 1);
}

// Block scans a 1024-chunk (256 thr x 4); writes local-exclusive values + chunk sum.
__global__ __launch_bounds__(256) void scan1_kernel(
    const int* __restrict__ cnt, int* __restrict__ off, int* __restrict__ bsum, int n)
{
    __shared__ int s[256];
    const int tid  = threadIdx.x;
    const int base = blockIdx.x * 1024 + tid * 4;
    int v0 = (base     < n) ? cnt[base]     : 0;
    int v1 = (base + 1 < n) ? cnt[base + 1] : 0;
    int v2 = (base + 2 < n) ? cnt[base + 2] : 0;
    int v3 = (base + 3 < n) ? cnt[base + 3] : 0;
    int tot = v0 + v1 + v2 + v3;
    s[tid] = tot;
    __syncthreads();
    for (int d = 1; d < 256; d <<= 1) {
        int y = (tid >= d) ? s[tid - d] : 0;
        __syncthreads();
        s[tid] += y;
        __syncthreads();
    }
    int excl = s[tid] - tot;
    if (base     < n) off[base]     = excl;
    if (base + 1 < n) off[base + 1] = excl + v0;
    if (base + 2 < n) off[base + 2] = excl + v0 + v1;
    if (base + 3 < n) off[base + 3] = excl + v0 + v1 + v2;
    if (tid == 255) bsum[blockIdx.x] = s[255];
}

// Single-wave exclusive scan of chunk sums (nb <= 1024).
__global__ void scan2_kernel(int* __restrict__ bsum, int nb)
{
    int lane = threadIdx.x;  // 64 threads
    int carry = 0;
    for (int base = 0; base < nb; base += 64) {
        int i = base + lane;
        int v = (i < nb) ? bsum[i] : 0;
        int x = v;
#pragma unroll
        for (int d = 1; d < 64; d <<= 1) {
            int y = __shfl_up(x, d, 64);
            if (lane >= d) x += y;
        }
        if (i < nb) bsum[i] = carry + x - v;
        carry += __shfl(x, 63, 64);
    }
}

// Add chunk base; duplicate into cursor; write off[n] = E.
__global__ __launch_bounds__(256) void scan3_kernel(
    int* __restrict__ off, int* __restrict__ cur, const int* __restrict__ bsum, int n, int E)
{
    int tid = blockIdx.x * blockDim.x + threadIdx.x;
    for (int i = tid; i < n; i += gridDim.x * blockDim.x) {
        int v = off[i] + bsum[i >> 10];
        off[i] = v;
        cur[i] = v;
    }
    if (tid == 0) off[n] = E;
}

__global__ __launch_bounds__(256) void scatter_kernel(
    const int* __restrict__ di, int* __restrict__ cur, int* __restrict__ perm, int E)
{
    for (int e = blockIdx.x * blockDim.x + threadIdx.x; e < E; e += gridDim.x * blockDim.x) {
        int slot = atomicAdd(&cur[di[e]], 1);
        perm[slot] = e;
    }
}

// ---------------------------------------------------------------------------
// Gather-aggregate: wave per node, lane = column.
// aggr[i][c] = sum over edges e with dst==i of relu(bn2(y2[e][c])).
__global__ __launch_bounds__(256) void agg_gather_kernel(
    const short* __restrict__ y2, const int* __restrict__ off, const int* __restrict__ perm,
    const float* __restrict__ scsh2, float* __restrict__ aggr, int N)
{
    const int lane = threadIdx.x & 63;
    const float sc = scsh2[lane], sh = scsh2[64 + lane];
    const int wid = (blockIdx.x * blockDim.x + threadIdx.x) >> 6;
    const int nw  = (gridDim.x * blockDim.x) >> 6;
    for (int i = wid; i < N; i += nw) {
        int a = off[i], b = off[i + 1];
        float acc = 0.f;
        int k = a;
        for (; k + 2 <= b; k += 2) {
            int e0 = perm[k], e1 = perm[k + 1];
            float v0 = bf2f(y2[(size_t)e0 * 64 + lane]);
            float v1 = bf2f(y2[(size_t)e1 * 64 + lane]);
            acc += fmaxf(fmaf(v0, sc, sh), 0.f);
            acc += fmaxf(fmaf(v1, sc, sh), 0.f);
        }
        if (k < b) {
            int e0 = perm[k];
            float v0 = bf2f(y2[(size_t)e0 * 64 + lane]);
            acc += fmaxf(fmaf(v0, sc, sh), 0.f);
        }
        aggr[(size_t)i * 64 + lane] = acc;
    }
}

// ---------------------------------------------------------------------------
__global__ void finalize_kernel(const float* __restrict__ raw,
                                const float* __restrict__ gamma,
                                const float* __restrict__ beta,
                                float* __restrict__ scsh, float inv_cnt)
{
    int c = threadIdx.x;
    float mu  = raw[c] * inv_cnt;
    float var = fmaf(raw[64 + c], inv_cnt, -mu * mu);
    float rs  = rsqrtf(var + BN_EPS);
    float sc  = rs * gamma[c];
    scsh[c]      = sc;
    scsh[64 + c] = fmaf(-mu, sc, beta[c]);
}

// ---------------------------------------------------------------------------
// Node layer 1: z = concat(bf16 h2, fp32 aggr) @ W1 + b1 -> overwrites z(=aggr); stats.
__global__ __launch_bounds__(256) void node_l1_kernel(
    const short* __restrict__ h2, float* __restrict__ z,
    const float* __restrict__ W1, const float* __restrict__ b1,
    float* __restrict__ stats, int Nn)
{
    __shared__ __align__(16) float xs[4][128];
    const int lane = threadIdx.x & 63;
    const int wv   = threadIdx.x >> 6;
    float w[128];
#pragma unroll
    for (int k = 0; k < 128; ++k) w[k] = W1[k * 64 + lane];
    const float bc = b1[lane];
    float s1 = 0.f, s2 = 0.f;
    const int wid = (blockIdx.x * blockDim.x + threadIdx.x) >> 6;
    const int nw  = (gridDim.x * blockDim.x) >> 6;
    for (int i = wid; i < Nn; i += nw) {
        xs[wv][lane]      = bf2f(h2[(size_t)i * 64 + lane]);
        xs[wv][64 + lane] = z[(size_t)i * 64 + lane];
        __builtin_amdgcn_wave_barrier();
        float a0 = 0.f, a1 = 0.f, a2 = 0.f, a3 = 0.f;
#pragma unroll
        for (int k = 0; k < 32; ++k) {
            a0 = fmaf(xs[wv][k],      w[k],      a0);
            a1 = fmaf(xs[wv][32 + k], w[32 + k], a1);
            a2 = fmaf(xs[wv][64 + k], w[64 + k], a2);
            a3 = fmaf(xs[wv][96 + k], w[96 + k], a3);
        }
        __builtin_amdgcn_wave_barrier();
        float acc = bc + ((a0 + a1) + (a2 + a3));
        z[(size_t)i * 64 + lane] = acc;
        s1 += acc; s2 += acc * acc;
    }
    atomicAdd(&stats[lane], s1);
    atomicAdd(&stats[64 + lane], s2);
}

// ---------------------------------------------------------------------------
// Node layer 2 (in place over z): t = relu(bn3(z)) @ W2 + b2; stats.
__global__ __launch_bounds__(256) void node_l2_kernel(
    float* __restrict__ z, const float* __restrict__ scsh,
    const float* __restrict__ W2, const float* __restrict__ b2,
    float* __restrict__ stats, int Nn)
{
    __shared__ __align__(16) float ys[4][64];
    const int lane = threadIdx.x & 63;
    const int wv   = threadIdx.x >> 6;
    float w[64];
#pragma unroll
    for (int k = 0; k < 64; ++k) w[k] = W2[k * 64 + lane];
    const float bc = b2[lane];
    const float sc = scsh[lane], sh = scsh[64 + lane];
    float s1 = 0.f, s2 = 0.f;
    const int wid = (blockIdx.x * blockDim.x + threadIdx.x) >> 6;
    const int nw  = (gridDim.x * blockDim.x) >> 6;
    for (int i = wid; i < Nn; i += nw) {
        float v = z[(size_t)i * 64 + lane];
        ys[wv][lane] = fmaxf(fmaf(v, sc, sh), 0.f);
        __builtin_amdgcn_wave_barrier();
        float a0 = 0.f, a1 = 0.f, a2 = 0.f, a3 = 0.f;
#pragma unroll
        for (int k = 0; k < 16; ++k) {
            a0 = fmaf(ys[wv][k],      w[k],      a0);
            a1 = fmaf(ys[wv][16 + k], w[16 + k], a1);
            a2 = fmaf(ys[wv][32 + k], w[32 + k], a2);
            a3 = fmaf(ys[wv][48 + k], w[48 + k], a3);
        }
        __builtin_amdgcn_wave_barrier();
        float acc = bc + ((a0 + a1) + (a2 + a3));
        z[(size_t)i * 64 + lane] = acc;
        s1 += acc; s2 += acc * acc;
    }
    atomicAdd(&stats[lane], s1);
    atomicAdd(&stats[64 + lane], s2);
}

// ---------------------------------------------------------------------------
// out[i] = relu(bn4(t[i])) . Wp + bp
__global__ __launch_bounds__(256) void pred_kernel(
    const float* __restrict__ t, const float* __restrict__ scsh,
    const float* __restrict__ Wp, const float* __restrict__ bp,
    float* __restrict__ out, int Nn)
{
    const int lane = threadIdx.x & 63;
    const float sc = scsh[lane], sh = scsh[64 + lane];
    const float wc = Wp[lane];
    const float bb = bp[0];
    const int wid = (blockIdx.x * blockDim.x + threadIdx.x) >> 6;
    const int nw  = (gridDim.x * blockDim.x) >> 6;
    for (int i = wid; i < Nn; i += nw) {
        float v = t[(size_t)i * 64 + lane];
        float p = fmaxf(fmaf(v, sc, sh), 0.f) * wc;
#pragma unroll
        for (int off = 32; off > 0; off >>= 1) p += __shfl_xor(p, off, 64);
        if (lane == 0) out[i] = p + bb;
    }
}

// ---------------------------------------------------------------------------
extern "C" void kernel_launch(void* const* d_in, const int* in_sizes, int n_in,
                              void* d_out, int out_size, void* d_ws, size_t ws_size,
                              hipStream_t stream)
{
    const float* pos  = (const float*)d_in[0];
    const float* vel  = (const float*)d_in[1];
    const int*   eidx = (const int*)d_in[2];
    const float* W_in = (const float*)d_in[3];
    const float* b_in = (const float*)d_in[4];
    const float* mW1  = (const float*)d_in[5];
    const float* mb1  = (const float*)d_in[6];
    const float* mg1  = (const float*)d_in[7];
    const float* mB1  = (const float*)d_in[8];
    const float* mW2  = (const float*)d_in[9];
    const float* mb2  = (const float*)d_in[10];
    const float* mg2  = (const float*)d_in[11];
    const float* mB2  = (const float*)d_in[12];
    const float* uW1  = (const float*)d_in[13];
    const float* ub1  = (const float*)d_in[14];
    const float* ug1  = (const float*)d_in[15];
    const float* uB1  = (const float*)d_in[16];
    const float* uW2  = (const float*)d_in[17];
    const float* ub2  = (const float*)d_in[18];
    const float* ug2  = (const float*)d_in[19];
    const float* uB2  = (const float*)d_in[20];
    const float* Wp   = (const float*)d_in[21];
    const float* bp   = (const float*)d_in[22];

    const int N = in_sizes[0] / 2;
    const int E = in_sizes[2] / 2;
    const int* src = eidx;       // edge_index[0] = source j
    const int* dst = eidx + E;   // edge_index[1] = dest   i (aggregation target)

    // workspace layout (~250.5 MB total; ws_size >= 256 MB proven in round 2)
    float* ws    = (float*)d_ws;
    float* stats = ws;                       // 4 stages x 128 (sum, sumsq)
    float* scsh  = ws + 512;                 // 4 stages x 128 (scale, shift)
    short* w1f   = (short*)(ws + 1024);      // 8192 shorts
    short* w2f   = w1f + 8192;               // 4096 shorts
    short* h2    = w2f + 4096;               // N*64 bf16
    float* aggr  = (float*)(h2 + (size_t)N * 64);   // N*64 fp32 (reused as z, t)
    short* y1    = (short*)(aggr + (size_t)N * 64); // E*64 bf16 (y1, then y2 in place)
    int*   cnt   = (int*)(y1 + (size_t)E * 64);     // N
    int*   off   = cnt + N;                          // N+1
    int*   cur   = off + N + 1;                      // N
    int*   perm  = cur + N;                          // E
    int*   bsum  = perm + E;                         // <= 1024
    float* out   = (float*)d_out;

    const int NB = (N + 1023) / 1024;

    hipMemsetAsync(stats, 0, 512 * sizeof(float), stream);
    hipMemsetAsync(cnt, 0, (size_t)N * sizeof(int), stream);

    prep_bfrag_kernel<<<4, 256, 0, stream>>>(mW1, w1f, 128);
    prep_bfrag_kernel<<<2, 256, 0, stream>>>(mW2, w2f, 64);

    embed_kernel<<<(N * 64 + 255) / 256, 256, 0, stream>>>(pos, vel, W_in, b_in, h2, N);

    // CSR permutation build (independent of edge MLP values)
    hist_kernel<<<1024, 256, 0, stream>>>(dst, cnt, E);
    scan1_kernel<<<NB, 256, 0, stream>>>(cnt, off, bsum, N);
    scan2_kernel<<<1, 64, 0, stream>>>(bsum, NB);
    scan3_kernel<<<512, 256, 0, stream>>>(off, cur, bsum, N, E);
    scatter_kernel<<<1024, 256, 0, stream>>>(dst, cur, perm, E);

    edge_p1_mfma<<<2048, 256, 0, stream>>>(h2, dst, src, w1f, mb1, y1, stats + 0, E);
    finalize_kernel<<<1, 64, 0, stream>>>(stats + 0, mg1, mB1, scsh + 0, 1.0f / (float)E);

    edge_p2_mfma<<<2048, 256, 0, stream>>>(y1, scsh + 0, w2f, mb2, stats + 128, E);
    finalize_kernel<<<1, 64, 0, stream>>>(stats + 128, mg2, mB2, scsh + 128, 1.0f / (float)E);

    agg_gather_kernel<<<2048, 256, 0, stream>>>(y1, off, perm, scsh + 128, aggr, N);

    node_l1_kernel<<<2048, 256, 0, stream>>>(h2, aggr, uW1, ub1, stats + 256, N);
    finalize_kernel<<<1, 64, 0, stream>>>(stats + 256, ug1, uB1, scsh + 256, 1.0f / (float)N);
    node_l2_kernel<<<1024, 256, 0, stream>>>(aggr, scsh + 256, uW2, ub2, stats + 384, N);
    finalize_kernel<<<1, 64, 0, stream>>>(stats + 384, ug2, uB2, scsh + 384, 1.0f / (float)N);
    pred_kernel<<<512, 256, 0, stream>>>(aggr, scsh + 384, Wp, bp, out, N);
}

// Round 5
// 684.631 us; speedup vs baseline: 3.5602x; 1.8274x over previous
//
#include <hip/hip_runtime.h>
#include <hip/hip_bf16.h>

#define BN_EPS 1e-5f

typedef short short8 __attribute__((ext_vector_type(8)));
typedef float f32x4  __attribute__((ext_vector_type(4)));
typedef unsigned int u32x2 __attribute__((ext_vector_type(2)));

__device__ inline float bf2f(short s) {
    unsigned u = ((unsigned)(unsigned short)s) << 16;
    return __builtin_bit_cast(float, u);
}
__device__ inline short f2bf(float f) {
    __hip_bfloat16 h = __float2bfloat16(f);
    return __builtin_bit_cast(short, h);
}
__device__ inline unsigned pack2(float a, float b) {
    return (unsigned)(unsigned short)f2bf(a) | ((unsigned)(unsigned short)f2bf(b) << 16);
}
__device__ inline f32x4 mfma16(short8 a, short8 b, f32x4 c) {
    return __builtin_amdgcn_mfma_f32_16x16x32_bf16(a, b, c, 0, 0, 0);
}

// ---------------------------------------------------------------------------
// W [K][64] fp32 -> per-lane bf16 fragments usable as A-operand (W^T blocks):
// slot s=(t*4+cb)*64+lane holds W[t*32+(lane>>4)*8+j][cb*16+(lane&15)], j=0..7
__global__ void prep_bfrag_kernel(const float* __restrict__ W, short* __restrict__ out, int K)
{
    int nt = K >> 5;
    int total = nt * 4 * 64;
    for (int s = blockIdx.x * blockDim.x + threadIdx.x; s < total; s += gridDim.x * blockDim.x) {
        int lane = s & 63, cb = (s >> 6) & 3, t = s >> 8;
        int n  = cb * 16 + (lane & 15);
        int k0 = t * 32 + ((lane >> 4) * 8);
        short8 v;
#pragma unroll
        for (int j = 0; j < 8; ++j) v[j] = f2bf(W[(k0 + j) * 64 + n]);
        *(short8*)(out + (size_t)s * 8) = v;
    }
}

// ---------------------------------------------------------------------------
// h2[i][c] = bf16([pos, vel] @ W_in + b_in)
__global__ __launch_bounds__(256) void embed_kernel(
    const float* __restrict__ pos, const float* __restrict__ vel,
    const float* __restrict__ W, const float* __restrict__ b,
    short* __restrict__ h2, int N)
{
    int t = blockIdx.x * blockDim.x + threadIdx.x;
    if (t >= N * 64) return;
    int i = t >> 6, c = t & 63;
    float acc = b[c];
    acc = fmaf(pos[2 * i],     W[c],       acc);
    acc = fmaf(pos[2 * i + 1], W[64 + c],  acc);
    acc = fmaf(vel[2 * i],     W[128 + c], acc);
    acc = fmaf(vel[2 * i + 1], W[192 + c], acc);
    h2[t] = f2bf(acc);
}

// ---------------------------------------------------------------------------
// Counting sort by dst.
__global__ __launch_bounds__(256) void hist_kernel(
    const int* __restrict__ di, int* __restrict__ cnt, int E)
{
    for (int e = blockIdx.x * blockDim.x + threadIdx.x; e < E; e += gridDim.x * blockDim.x)
        atomicAdd(&cnt[di[e]], 1);
}

__global__ __launch_bounds__(256) void scan1_kernel(
    const int* __restrict__ cnt, int* __restrict__ off, int* __restrict__ bsum, int n)
{
    __shared__ int s[256];
    const int tid  = threadIdx.x;
    const int base = blockIdx.x * 1024 + tid * 4;
    int v0 = (base     < n) ? cnt[base]     : 0;
    int v1 = (base + 1 < n) ? cnt[base + 1] : 0;
    int v2 = (base + 2 < n) ? cnt[base + 2] : 0;
    int v3 = (base + 3 < n) ? cnt[base + 3] : 0;
    int tot = v0 + v1 + v2 + v3;
    s[tid] = tot;
    __syncthreads();
    for (int d = 1; d < 256; d <<= 1) {
        int y = (tid >= d) ? s[tid - d] : 0;
        __syncthreads();
        s[tid] += y;
        __syncthreads();
    }
    int excl = s[tid] - tot;
    if (base     < n) off[base]     = excl;
    if (base + 1 < n) off[base + 1] = excl + v0;
    if (base + 2 < n) off[base + 2] = excl + v0 + v1;
    if (base + 3 < n) off[base + 3] = excl + v0 + v1 + v2;
    if (tid == 255) bsum[blockIdx.x] = s[255];
}

__global__ void scan2_kernel(int* __restrict__ bsum, int nb)
{
    int lane = threadIdx.x;  // 64 threads
    int carry = 0;
    for (int base = 0; base < nb; base += 64) {
        int i = base + lane;
        int v = (i < nb) ? bsum[i] : 0;
        int x = v;
#pragma unroll
        for (int d = 1; d < 64; d <<= 1) {
            int y = __shfl_up(x, d, 64);
            if (lane >= d) x += y;
        }
        if (i < nb) bsum[i] = carry + x - v;
        carry += __shfl(x, 63, 64);
    }
}

__global__ __launch_bounds__(256) void scan3_kernel(
    int* __restrict__ off, int* __restrict__ cur, const int* __restrict__ bsum, int n, int E)
{
    int tid = blockIdx.x * blockDim.x + threadIdx.x;
    for (int i = tid; i < n; i += gridDim.x * blockDim.x) {
        int v = off[i] + bsum[i >> 10];
        off[i] = v;
        cur[i] = v;
    }
    if (tid == 0) off[n] = E;
}

// Writes dst/src index streams in dst-sorted slot order.
__global__ __launch_bounds__(256) void scatter_kernel(
    const int* __restrict__ di, const int* __restrict__ sj,
    int* __restrict__ cur, int* __restrict__ dstp, int* __restrict__ srcp, int E)
{
    for (int e = blockIdx.x * blockDim.x + threadIdx.x; e < E; e += gridDim.x * blockDim.x) {
        int d = di[e];
        int slot = atomicAdd(&cur[d], 1);
        dstp[slot] = d;
        srcp[slot] = sj[e];
    }
}

// ---------------------------------------------------------------------------
// Unified 2-layer MLP kernel (transposed MFMA: A=W^T frags, B=activations^T).
// FUSE=false: GEMM1 only, accumulate raw col stats (no store).
// FUSE=true : GEMM1 -> relu(bn_mid) -> LDS transpose -> GEMM2 -> stats + store.
// GATHER=true: rows via idxA/idxB into ptrA/ptrB; else identity rows.
// Dynamic LDS: FUSE ? (4*1280*2 + 2048) : 2048 bytes.
template <bool FUSE, bool GATHER>
__global__ __launch_bounds__(256) void mlp_mfma_kernel(
    const short* __restrict__ ptrA, const short* __restrict__ ptrB,
    const int* __restrict__ idxA, const int* __restrict__ idxB,
    const short* __restrict__ wf1, const short* __restrict__ wf2,
    const float* __restrict__ scsh, float* __restrict__ stats,
    short* __restrict__ outp, int M)
{
    extern __shared__ short xs[];
    const int lane = threadIdx.x & 63;
    const int wv   = threadIdx.x >> 6;
    const int m16  = lane & 15;
    const int quad = lane >> 4;
    short* lds = xs + wv * 1280;                     // FUSE only: 16 rows x 80 shorts
    float* sred = (float*)(xs + (FUSE ? 5120 : 0));  // 4 x 128 block-reduce area

    short8 w1r[16];
#pragma unroll
    for (int s = 0; s < 16; ++s) w1r[s] = *(const short8*)(wf1 + ((size_t)s * 64 + lane) * 8);
    short8 w2r[8];
    float sc_m[16], sh_m[16];
    if constexpr (FUSE) {
#pragma unroll
        for (int s = 0; s < 8; ++s) w2r[s] = *(const short8*)(wf2 + ((size_t)s * 64 + lane) * 8);
#pragma unroll
        for (int u = 0; u < 16; ++u) {
            int ch = (u >> 2) * 16 + quad * 4 + (u & 3);
            sc_m[u] = scsh[ch];
            sh_m[u] = scsh[64 + ch];
        }
    }
    float s1[16], s2[16];
#pragma unroll
    for (int u = 0; u < 16; ++u) { s1[u] = 0.f; s2[u] = 0.f; }

    const int wid = (blockIdx.x * blockDim.x + threadIdx.x) >> 6;
    const int nw  = (gridDim.x * blockDim.x) >> 6;
    const int ntiles = M >> 4;
    for (int tile = wid; tile < ntiles; tile += nw) {
        const int k0 = tile << 4;
        const int e  = k0 + m16;
        const int ra = GATHER ? idxA[e] : e;
        const int rb = GATHER ? idxB[e] : e;
        const short* pa = ptrA + (size_t)ra * 64;
        const short* pb = ptrB + (size_t)rb * 64;
        short8 a0 = *(const short8*)(pa + quad * 8);
        short8 a1 = *(const short8*)(pa + 32 + quad * 8);
        short8 a2 = *(const short8*)(pb + quad * 8);
        short8 a3 = *(const short8*)(pb + 32 + quad * 8);
#pragma unroll
        for (int cb = 0; cb < 4; ++cb) {
            f32x4 c = {0.f, 0.f, 0.f, 0.f};
            c = mfma16(w1r[0 * 4 + cb], a0, c);
            c = mfma16(w1r[1 * 4 + cb], a1, c);
            c = mfma16(w1r[2 * 4 + cb], a2, c);
            c = mfma16(w1r[3 * 4 + cb], a3, c);
            if constexpr (!FUSE) {
#pragma unroll
                for (int r = 0; r < 4; ++r) {
                    float v = c[r];
                    s1[cb * 4 + r] += v;
                    s2[cb * 4 + r] += v * v;
                }
            } else {
                float r0 = fmaxf(fmaf(c[0], sc_m[cb * 4 + 0], sh_m[cb * 4 + 0]), 0.f);
                float r1 = fmaxf(fmaf(c[1], sc_m[cb * 4 + 1], sh_m[cb * 4 + 1]), 0.f);
                float r2 = fmaxf(fmaf(c[2], sc_m[cb * 4 + 2], sh_m[cb * 4 + 2]), 0.f);
                float r3 = fmaxf(fmaf(c[3], sc_m[cb * 4 + 3], sh_m[cb * 4 + 3]), 0.f);
                u32x2 p = { pack2(r0, r1), pack2(r2, r3) };
                *(u32x2*)(lds + m16 * 80 + cb * 16 + quad * 4) = p;
            }
        }
        if constexpr (FUSE) {
            __builtin_amdgcn_wave_barrier();
            short8 b0 = *(const short8*)(lds + m16 * 80 + quad * 8);
            short8 b1 = *(const short8*)(lds + m16 * 80 + 32 + quad * 8);
            __builtin_amdgcn_wave_barrier();
#pragma unroll
            for (int cb = 0; cb < 4; ++cb) {
                f32x4 c = {0.f, 0.f, 0.f, 0.f};
                c = mfma16(w2r[0 * 4 + cb], b0, c);
                c = mfma16(w2r[1 * 4 + cb], b1, c);
#pragma unroll
                for (int r = 0; r < 4; ++r) {
                    float v = c[r];
                    s1[cb * 4 + r] += v;
                    s2[cb * 4 + r] += v * v;
                }
                u32x2 p = { pack2(c[0], c[1]), pack2(c[2], c[3]) };
                *(u32x2*)(outp + (size_t)(k0 + m16) * 64 + cb * 16 + quad * 4) = p;
            }
        }
    }
    // reduce over the 16 edge-lanes (same quad holds same channels)
#pragma unroll
    for (int u = 0; u < 16; ++u) {
#pragma unroll
        for (int d = 1; d < 16; d <<= 1) {
            s1[u] += __shfl_xor(s1[u], d, 64);
            s2[u] += __shfl_xor(s2[u], d, 64);
        }
    }
    if (m16 == 0) {
#pragma unroll
        for (int u = 0; u < 16; ++u) {
            int ch = (u >> 2) * 16 + quad * 4 + (u & 3);
            sred[wv * 128 + ch]      = s1[u];
            sred[wv * 128 + 64 + ch] = s2[u];
        }
    }
    __syncthreads();
    if (threadIdx.x < 128) {
        float t = sred[threadIdx.x] + sred[128 + threadIdx.x] +
                  sred[256 + threadIdx.x] + sred[384 + threadIdx.x];
        atomicAdd(&stats[threadIdx.x], t);
    }
}

// ---------------------------------------------------------------------------
// aggr2[i][c] = bf16( sum over slots k in [off[i],off[i+1]) of relu(bn2(y2p[k][c])) )
__global__ __launch_bounds__(256) void agg_gather_kernel(
    const short* __restrict__ y2p, const int* __restrict__ off,
    const float* __restrict__ scsh2, short* __restrict__ aggr2, int N)
{
    const int lane = threadIdx.x & 63;
    const float sc = scsh2[lane], sh = scsh2[64 + lane];
    const int wid = (blockIdx.x * blockDim.x + threadIdx.x) >> 6;
    const int nw  = (gridDim.x * blockDim.x) >> 6;
    for (int i = wid; i < N; i += nw) {
        int a = off[i], b = off[i + 1];
        float acc = 0.f;
        int k = a;
        for (; k + 2 <= b; k += 2) {
            float v0 = bf2f(y2p[(size_t)k * 64 + lane]);
            float v1 = bf2f(y2p[(size_t)(k + 1) * 64 + lane]);
            acc += fmaxf(fmaf(v0, sc, sh), 0.f);
            acc += fmaxf(fmaf(v1, sc, sh), 0.f);
        }
        if (k < b) {
            float v0 = bf2f(y2p[(size_t)k * 64 + lane]);
            acc += fmaxf(fmaf(v0, sc, sh), 0.f);
        }
        aggr2[(size_t)i * 64 + lane] = f2bf(acc);
    }
}

// ---------------------------------------------------------------------------
__global__ void finalize_kernel(const float* __restrict__ raw,
                                const float* __restrict__ gamma,
                                const float* __restrict__ beta,
                                float* __restrict__ scsh, float inv_cnt)
{
    int c = threadIdx.x;
    float mu  = raw[c] * inv_cnt;
    float var = fmaf(raw[64 + c], inv_cnt, -mu * mu);
    float rs  = rsqrtf(var + BN_EPS);
    float sc  = rs * gamma[c];
    scsh[c]      = sc;
    scsh[64 + c] = fmaf(-mu, sc, beta[c]);
}

// ---------------------------------------------------------------------------
// out[i] = relu(bn4(z2[i])) . Wp + bp
__global__ __launch_bounds__(256) void pred_kernel(
    const short* __restrict__ z2, const float* __restrict__ scsh,
    const float* __restrict__ Wp, const float* __restrict__ bp,
    float* __restrict__ out, int Nn)
{
    const int lane = threadIdx.x & 63;
    const float sc = scsh[lane], sh = scsh[64 + lane];
    const float wc = Wp[lane];
    const float bb = bp[0];
    const int wid = (blockIdx.x * blockDim.x + threadIdx.x) >> 6;
    const int nw  = (gridDim.x * blockDim.x) >> 6;
    for (int i = wid; i < Nn; i += nw) {
        float v = bf2f(z2[(size_t)i * 64 + lane]);
        float p = fmaxf(fmaf(v, sc, sh), 0.f) * wc;
#pragma unroll
        for (int off = 32; off > 0; off >>= 1) p += __shfl_xor(p, off, 64);
        if (lane == 0) out[i] = p + bb;
    }
}

// ---------------------------------------------------------------------------
extern "C" void kernel_launch(void* const* d_in, const int* in_sizes, int n_in,
                              void* d_out, int out_size, void* d_ws, size_t ws_size,
                              hipStream_t stream)
{
    const float* pos  = (const float*)d_in[0];
    const float* vel  = (const float*)d_in[1];
    const int*   eidx = (const int*)d_in[2];
    const float* W_in = (const float*)d_in[3];
    const float* b_in = (const float*)d_in[4];
    const float* mW1  = (const float*)d_in[5];
    const float* mg1  = (const float*)d_in[7];
    const float* mB1  = (const float*)d_in[8];
    const float* mW2  = (const float*)d_in[9];
    const float* mg2  = (const float*)d_in[11];
    const float* mB2  = (const float*)d_in[12];
    const float* uW1  = (const float*)d_in[13];
    const float* ug1  = (const float*)d_in[15];
    const float* uB1  = (const float*)d_in[16];
    const float* uW2  = (const float*)d_in[17];
    const float* ug2  = (const float*)d_in[19];
    const float* uB2  = (const float*)d_in[20];
    const float* Wp   = (const float*)d_in[21];
    const float* bp   = (const float*)d_in[22];
    // NOTE: mb1/mb2/ub1/ub2 (d_in[6,10,14,18]) cancel exactly through batch-stat BN.

    const int N = in_sizes[0] / 2;
    const int E = in_sizes[2] / 2;
    const int* src = eidx;       // edge_index[0] = source j
    const int* dst = eidx + E;   // edge_index[1] = dest   i (aggregation target)

    // workspace layout (~244 MB)
    float* ws    = (float*)d_ws;
    float* stats = ws;                       // 4 x 128 raw (sum, sumsq)
    float* scsh  = ws + 512;                 // 4 x 128 (scale, shift)
    short* w1f   = (short*)(ws + 1024);      // 8192
    short* w2f   = w1f + 8192;               // 4096
    short* nw1f  = w2f + 4096;               // 8192
    short* nw2f  = nw1f + 8192;              // 4096
    short* h2    = nw2f + 4096;              // N*64 bf16
    short* aggr2 = h2 + (size_t)N * 64;      // N*64 bf16
    short* y2p   = aggr2 + (size_t)N * 64;   // E*64 bf16 (perm order)
    int*   cnt   = (int*)(y2p + (size_t)E * 64); // N
    int*   off   = cnt + N;                  // N+4 (padded)
    int*   cur   = off + N + 4;              // N
    int*   dstp  = cur + N;                  // E
    int*   srcp  = dstp + E;                 // E
    int*   bsum  = srcp + E;                 // <= 1024
    short* z2    = (short*)dstp;             // N*64 bf16 overlays dstp/srcp (dead after edge pass)
    float* out   = (float*)d_out;

    const int NB = (N + 1023) / 1024;
    const int FUSE_LDS  = 4 * 1280 * 2 + 2048;
    const int STAT_LDS  = 2048;

    hipMemsetAsync(stats, 0, 512 * sizeof(float), stream);
    hipMemsetAsync(cnt, 0, (size_t)N * sizeof(int), stream);

    prep_bfrag_kernel<<<4, 256, 0, stream>>>(mW1, w1f, 128);
    prep_bfrag_kernel<<<2, 256, 0, stream>>>(mW2, w2f, 64);
    prep_bfrag_kernel<<<4, 256, 0, stream>>>(uW1, nw1f, 128);
    prep_bfrag_kernel<<<2, 256, 0, stream>>>(uW2, nw2f, 64);

    embed_kernel<<<(N * 64 + 255) / 256, 256, 0, stream>>>(pos, vel, W_in, b_in, h2, N);

    hist_kernel<<<1024, 256, 0, stream>>>(dst, cnt, E);
    scan1_kernel<<<NB, 256, 0, stream>>>(cnt, off, bsum, N);
    scan2_kernel<<<1, 64, 0, stream>>>(bsum, NB);
    scan3_kernel<<<512, 256, 0, stream>>>(off, cur, bsum, N, E);
    scatter_kernel<<<1024, 256, 0, stream>>>(dst, src, cur, dstp, srcp, E);

    // Edge MLP: stats-only pass, then fused recompute+GEMM2 (writes y2p in slot order)
    mlp_mfma_kernel<false, true><<<2048, 256, STAT_LDS, stream>>>(
        h2, h2, dstp, srcp, w1f, nullptr, nullptr, stats + 0, nullptr, E);
    finalize_kernel<<<1, 64, 0, stream>>>(stats + 0, mg1, mB1, scsh + 0, 1.0f / (float)E);
    mlp_mfma_kernel<true, true><<<2048, 256, FUSE_LDS, stream>>>(
        h2, h2, dstp, srcp, w1f, w2f, scsh + 0, stats + 128, y2p, E);
    finalize_kernel<<<1, 64, 0, stream>>>(stats + 128, mg2, mB2, scsh + 128, 1.0f / (float)E);

    agg_gather_kernel<<<2048, 256, 0, stream>>>(y2p, off, scsh + 128, aggr2, N);

    // Node MLP: same structure, identity rows; z2 overlays dstp/srcp
    mlp_mfma_kernel<false, false><<<1024, 256, STAT_LDS, stream>>>(
        h2, aggr2, nullptr, nullptr, nw1f, nullptr, nullptr, stats + 256, nullptr, N);
    finalize_kernel<<<1, 64, 0, stream>>>(stats + 256, ug1, uB1, scsh + 256, 1.0f / (float)N);
    mlp_mfma_kernel<true, false><<<1024, 256, FUSE_LDS, stream>>>(
        h2, aggr2, nullptr, nullptr, nw1f, nw2f, scsh + 256, stats + 384, z2, N);
    finalize_kernel<<<1, 64, 0, stream>>>(stats + 384, ug2, uB2, scsh + 384, 1.0f / (float)N);

    pred_kernel<<<512, 256, 0, stream>>>(z2, scsh + 384, Wp, bp, out, N);
}